// Round 1
// baseline (534.910 us; speedup 1.0000x reference)
//
#include <hip/hip_runtime.h>
#include <math.h>

// Problem constants (from reference setup_inputs):
// B=8 images, N=256*256 pixels/image, P=200 prototypes, C=20 classes.
constexpr int B = 8;
constexpr int N = 256 * 256;
constexpr int P = 200;
constexpr int C = 20;
constexpr int NSLOT = B * C;        // 160 (image,class) accumulator slots
constexpr int MAXNNZ = P * C;       // worst-case nonzeros in identity matrix

// ---------------------------------------------------------------------------
// Kernel 1: zero accumulators + build sparse (prototype, weight) lists per
// class from prototype_class_identity [P, C]. Keeps full generality (doesn't
// assume block-diagonal one-hot) while letting the main kernel touch only the
// nonzero prototypes for each pixel's class.
// ---------------------------------------------------------------------------
__global__ __launch_bounds__(256) void setup_kernel(
    const float* __restrict__ ident,   // [P, C]
    float* __restrict__ ws_acc,        // 2*NSLOT floats: sums then counts
    int* __restrict__ ws_off,          // [C+1]
    int* __restrict__ ws_idx,          // [MAXNNZ]
    float* __restrict__ ws_w) {        // [MAXNNZ]
  __shared__ int cnts[C];
  __shared__ int soff[C + 1];
  const int t = threadIdx.x;

  // zero global accumulators (ws is poisoned 0xAA before every launch)
  for (int i = t; i < 2 * NSLOT; i += blockDim.x) ws_acc[i] = 0.0f;

  if (t < C) {
    int c = 0;
    for (int p = 0; p < P; ++p)
      if (ident[p * C + t] != 0.0f) ++c;
    cnts[t] = c;
  }
  __syncthreads();
  if (t == 0) {
    int acc = 0;
    for (int c = 0; c < C; ++c) { soff[c] = acc; acc += cnts[c]; }
    soff[C] = acc;
  }
  __syncthreads();
  if (t <= C) ws_off[t] = soff[t];
  if (t < C) {
    int o = soff[t];
    for (int p = 0; p < P; ++p) {
      float v = ident[p * C + t];
      if (v != 0.0f) { ws_idx[o] = p; ws_w[o] = v; ++o; }
    }
  }
}

// ---------------------------------------------------------------------------
// Kernel 2: the heavy pass. Grid-stride over all B*N pixels. For each valid
// pixel (label in [0,C)), read only the nonzero-weight prototype activations
// (10 floats = 40 B instead of the full 800-B row), accumulate
// sum(|a|*w) and a count into per-block LDS slots, flush once per block via
// global atomics.
// ---------------------------------------------------------------------------
__global__ __launch_bounds__(256) void main_kernel(
    const float* __restrict__ A,        // [B*N, P]
    const int* __restrict__ labels,     // [B*N]
    const int* __restrict__ ws_off,
    const int* __restrict__ ws_idx,
    const float* __restrict__ ws_w,
    float* __restrict__ ws_acc) {       // sums[NSLOT] then counts[NSLOT]
  __shared__ float s_sum[NSLOT];
  __shared__ float s_cnt[NSLOT];
  __shared__ int s_off[C + 1];
  __shared__ int s_idx[MAXNNZ];
  __shared__ float s_w[MAXNNZ];

  const int t = threadIdx.x;
  for (int i = t; i < NSLOT; i += blockDim.x) { s_sum[i] = 0.0f; s_cnt[i] = 0.0f; }
  for (int i = t; i <= C; i += blockDim.x) s_off[i] = ws_off[i];
  __syncthreads();
  const int total = s_off[C];
  for (int i = t; i < total; i += blockDim.x) { s_idx[i] = ws_idx[i]; s_w[i] = ws_w[i]; }
  __syncthreads();

  const long long NP = (long long)B * N;
  const long long stride = (long long)gridDim.x * blockDim.x;
  for (long long i = (long long)blockIdx.x * blockDim.x + t; i < NP; i += stride) {
    const int lab = labels[i] - 1;
    if (lab >= 0 && lab < C) {
      const float* row = A + (size_t)i * P;
      const int o0 = s_off[lab];
      const int o1 = s_off[lab + 1];
      float s = 0.0f;
      #pragma unroll 2
      for (int k = o0; k < o1; ++k) s += fabsf(row[s_idx[k]]) * s_w[k];
      const int b = (int)(i / N);
      const int slot = b * C + lab;
      atomicAdd(&s_sum[slot], s);
      atomicAdd(&s_cnt[slot], 1.0f);
    }
  }
  __syncthreads();
  for (int i = t; i < NSLOT; i += blockDim.x) {
    const float cv = s_cnt[i];
    if (cv != 0.0f) {
      atomicAdd(&ws_acc[i], s_sum[i]);
      atomicAdd(&ws_acc[NSLOT + i], cv);
    }
  }
}

// ---------------------------------------------------------------------------
// Kernel 3: scalar epilogue. class_norm[b][c] = sum / max(cnt,1) / max(pc,1);
// mean over valid (cnt>0 && proto_count>0) slots.
// ---------------------------------------------------------------------------
__global__ __launch_bounds__(256) void final_kernel(
    const float* __restrict__ ident,
    const float* __restrict__ ws_acc,
    float* __restrict__ out) {
  __shared__ float pc[C];
  __shared__ float red_num[256];
  __shared__ float red_den[256];
  const int t = threadIdx.x;
  if (t < C) {
    float s = 0.0f;
    for (int p = 0; p < P; ++p) s += ident[p * C + t];
    pc[t] = s;
  }
  __syncthreads();
  float num = 0.0f, den = 0.0f;
  for (int i = t; i < NSLOT; i += blockDim.x) {
    const float cnt = ws_acc[NSLOT + i];
    const float p = pc[i % C];
    if (cnt > 0.0f && p > 0.0f) {
      num += ws_acc[i] / fmaxf(cnt, 1.0f) / fmaxf(p, 1.0f);
      den += 1.0f;
    }
  }
  red_num[t] = num;
  red_den[t] = den;
  __syncthreads();
  for (int s = 128; s > 0; s >>= 1) {
    if (t < s) { red_num[t] += red_num[t + s]; red_den[t] += red_den[t + s]; }
    __syncthreads();
  }
  if (t == 0) out[0] = red_num[0] / fmaxf(red_den[0], 1.0f);
}

extern "C" void kernel_launch(void* const* d_in, const int* in_sizes, int n_in,
                              void* d_out, int out_size, void* d_ws, size_t ws_size,
                              hipStream_t stream) {
  const float* A      = (const float*)d_in[0];   // [B, N, P] fp32
  const int*   labels = (const int*)d_in[1];     // [B, H, W] int
  const float* ident  = (const float*)d_in[2];   // [P, C] fp32
  float* out = (float*)d_out;

  // workspace layout (all 4-byte aligned):
  float* ws_acc = (float*)d_ws;                  // 2*NSLOT floats
  int*   ws_off = (int*)(ws_acc + 2 * NSLOT);    // C+1 ints
  int*   ws_idx = ws_off + (C + 1);              // MAXNNZ ints
  float* ws_w   = (float*)(ws_idx + MAXNNZ);     // MAXNNZ floats

  setup_kernel<<<1, 256, 0, stream>>>(ident, ws_acc, ws_off, ws_idx, ws_w);
  main_kernel<<<512, 256, 0, stream>>>(A, labels, ws_off, ws_idx, ws_w, ws_acc);
  final_kernel<<<1, 256, 0, stream>>>(ident, ws_acc, out);
}